// Round 1
// 371.474 us; speedup vs baseline: 1.1467x; 1.1467x over previous
//
#include <hip/hip_runtime.h>
#include <hip/hip_bf16.h>
#include <math.h>

// Problem constants (from reference)
#define N_HEADN 50000
#define N_TAILN 50000
#define NE      800000
#define F_IN    256
#define HH      4
#define HD      256   // H*D
#define FE      64
#define N_ETYPES 5
#define NEG_SLOPE 0.2f
#define NB_SCAN ((N_HEADN + 255) / 256)   // 196

typedef __attribute__((ext_vector_type(8))) short bf16x8;
typedef __attribute__((ext_vector_type(4))) float f32x4;

// bf16 <-> fp32 (RNE), bit-level
static __device__ __forceinline__ unsigned short f2bf(float f) {
    unsigned u = __float_as_uint(f);
    return (unsigned short)((u + 0x7FFF + ((u >> 16) & 1)) >> 16);
}
static __device__ __forceinline__ float bf2f(unsigned short u) {
    return __uint_as_float((unsigned)u << 16);
}

// ---------------------------------------------------------------------------
// K_prep (fused): block 0 -> waT, block 1 -> he, blocks 2..257 -> Wt
//   waT[h][k] = sum_d a_l[h][d] * W[k][h*64+d]
//   he[ty][h] = sum_k edge_emb[ty][k] * (sum_f a_e[h][f] * W_e[k][h*64+f])
//   Wt[n][k]  = bf16(W[k][n])
// ---------------------------------------------------------------------------
__global__ __launch_bounds__(256) void prep_kernel(const float* __restrict__ W,
                                                   const float* __restrict__ a_l,
                                                   const float* __restrict__ W_e,
                                                   const float* __restrict__ a_e,
                                                   const float* __restrict__ edge_emb,
                                                   float* __restrict__ waT,
                                                   float* __restrict__ heo,
                                                   short* __restrict__ Wt) {
    const int b = blockIdx.x;
    if (b == 0) {
        int k = threadIdx.x;   // 0..255
        #pragma unroll
        for (int h = 0; h < HH; ++h) {
            float s = 0.f;
            for (int d = 0; d < 64; ++d) s += a_l[h * 64 + d] * W[(size_t)k * HD + h * 64 + d];
            waT[h * 256 + k] = s;
        }
    } else if (b == 1) {
        __shared__ float wae[FE][HH];
        int t = threadIdx.x;          // 256 threads = 64 k x 4 h
        int k = t >> 2, h = t & 3;
        float s = 0.f;
        for (int f = 0; f < 64; ++f) s += a_e[h * 64 + f] * W_e[(size_t)k * (FE * HH) + h * 64 + f];
        wae[k][h] = s;
        __syncthreads();
        if (t < N_ETYPES * HH) {
            int ty = t >> 2, hh = t & 3;
            float acc = 0.f;
            for (int kk = 0; kk < FE; ++kk) acc += edge_emb[ty * FE + kk] * wae[kk][hh];
            heo[ty * HH + hh] = acc;
        }
    } else {
        int n = b - 2, k = threadIdx.x;
        Wt[(size_t)n * 256 + k] = (short)f2bf(W[(size_t)k * 256 + n]);
    }
}

// ---------------------------------------------------------------------------
// K1: histogram of head indices
// ---------------------------------------------------------------------------
__global__ void hist_kernel(const int* __restrict__ head, int* __restrict__ counts) {
    int e = blockIdx.x * 256 + threadIdx.x;   // NE % 256 == 0
    atomicAdd(&counts[head[e]], 1);
}

// ---------------------------------------------------------------------------
// K2a/b/c: parallel 3-phase exclusive scan of counts -> row_start, cursor
// ---------------------------------------------------------------------------
__global__ void blocksum_kernel(const int* __restrict__ counts, int* __restrict__ blockSums) {
    __shared__ int s[256];
    int t = threadIdx.x, j = blockIdx.x * 256 + t;
    s[t] = (j < N_HEADN) ? counts[j] : 0;
    __syncthreads();
    for (int off = 128; off > 0; off >>= 1) {
        if (t < off) s[t] += s[t + off];
        __syncthreads();
    }
    if (t == 0) blockSums[blockIdx.x] = s[0];
}

__global__ void blockscan_kernel(const int* __restrict__ blockSums, int* __restrict__ blockOff) {
    __shared__ int s[256];
    int t = threadIdx.x;
    int v = (t < NB_SCAN) ? blockSums[t] : 0;
    s[t] = v;
    __syncthreads();
    for (int off = 1; off < 256; off <<= 1) {
        int u = (t >= off) ? s[t - off] : 0;
        __syncthreads();
        s[t] += u;
        __syncthreads();
    }
    if (t < NB_SCAN) blockOff[t] = s[t] - v;
}

__global__ void rowstart_kernel(const int* __restrict__ counts, const int* __restrict__ blockOff,
                                int* __restrict__ row_start, int* __restrict__ cursor) {
    __shared__ int s[256];
    int t = threadIdx.x, j = blockIdx.x * 256 + t;
    int c = (j < N_HEADN) ? counts[j] : 0;
    s[t] = c;
    __syncthreads();
    for (int off = 1; off < 256; off <<= 1) {
        int u = (t >= off) ? s[t - off] : 0;
        __syncthreads();
        s[t] += u;
        __syncthreads();
    }
    int excl = blockOff[blockIdx.x] + s[t] - c;
    if (j < N_HEADN) {
        row_start[j] = excl;
        cursor[j]    = excl;
        if (j == N_HEADN - 1) row_start[N_HEADN] = excl + c;
    }
}

// ---------------------------------------------------------------------------
// K3a: hl = X_head @ waT^T  (thin GEMM, memory-bound). One wave per row.
// ---------------------------------------------------------------------------
__global__ __launch_bounds__(256) void head_dot_kernel(const float* __restrict__ X,
                                                       const float* __restrict__ waT,
                                                       float* __restrict__ hl) {
    const int wave = threadIdx.x >> 6;
    const int lane = threadIdx.x & 63;
    const int n = blockIdx.x * 4 + wave;   // N_HEADN % 4 == 0
    float4 x = ((const float4*)(X + (size_t)n * F_IN))[lane];
    float p[HH];
    #pragma unroll
    for (int h = 0; h < HH; ++h) {
        float4 w = ((const float4*)(waT + h * 256))[lane];
        p[h] = x.x * w.x + x.y * w.y + x.z * w.z + x.w * w.w;
    }
    #pragma unroll
    for (int off = 1; off < 64; off <<= 1) {
        #pragma unroll
        for (int h = 0; h < HH; ++h) p[h] += __shfl_xor(p[h], off);
    }
    if (lane < HH) hl[(size_t)n * HH + lane] = p[lane];
}

// ---------------------------------------------------------------------------
// K3b: h_tail = X_tail @ W via bf16 MFMA (16x16x32), fp32 accum.
// (unchanged from verified version)
// ---------------------------------------------------------------------------
__global__ __launch_bounds__(256) void proj_mfma_kernel(const float* __restrict__ X,
                                                        const short* __restrict__ Wt,
                                                        const float* __restrict__ a,
                                                        unsigned short* __restrict__ h_out,
                                                        float* __restrict__ dot_out,
                                                        int N) {
    const int tid  = threadIdx.x;
    const int w    = tid >> 6;          // wave = head index
    const int lane = tid & 63;
    const int quad = lane >> 4;
    const int l15  = lane & 15;
    const int n0   = blockIdx.x * 32;

    const bool valid1 = (n0 + 16) < N;  // tile 1 present (N % 16 == 0)

    f32x4 acc[2][4];
    #pragma unroll
    for (int mt = 0; mt < 2; ++mt)
        #pragma unroll
        for (int ct = 0; ct < 4; ++ct)
            acc[mt][ct] = (f32x4){0.f, 0.f, 0.f, 0.f};

    const float* xbase0 = X + (size_t)(n0 + l15) * F_IN + quad * 8;
    const float* xbase1 = X + (size_t)(n0 + 16 + l15) * F_IN + quad * 8;
    const short* wbase  = Wt + (size_t)(w * 64 + l15) * 256 + quad * 8;

    for (int k0 = 0; k0 < 256; k0 += 32) {
        bf16x8 afrag[2];
        #pragma unroll
        for (int mt = 0; mt < 2; ++mt) {
            if (mt == 1 && !valid1) break;
            const float* xp = (mt == 0 ? xbase0 : xbase1) + k0;
            float4 x0 = *(const float4*)xp;
            float4 x1 = *(const float4*)(xp + 4);
            bf16x8 af;
            af[0] = (short)f2bf(x0.x); af[1] = (short)f2bf(x0.y);
            af[2] = (short)f2bf(x0.z); af[3] = (short)f2bf(x0.w);
            af[4] = (short)f2bf(x1.x); af[5] = (short)f2bf(x1.y);
            af[6] = (short)f2bf(x1.z); af[7] = (short)f2bf(x1.w);
            afrag[mt] = af;
        }
        #pragma unroll
        for (int ct = 0; ct < 4; ++ct) {
            bf16x8 bfrag = *(const bf16x8*)(wbase + (size_t)ct * 16 * 256 + k0);
            acc[0][ct] = __builtin_amdgcn_mfma_f32_16x16x32_bf16(afrag[0], bfrag, acc[0][ct], 0, 0, 0);
            if (valid1)
                acc[1][ct] = __builtin_amdgcn_mfma_f32_16x16x32_bf16(afrag[1], bfrag, acc[1][ct], 0, 0, 0);
        }
    }

    float av[4];
    #pragma unroll
    for (int ct = 0; ct < 4; ++ct) av[ct] = a[w * 64 + ct * 16 + l15];

    #pragma unroll
    for (int mt = 0; mt < 2; ++mt) {
        if (mt == 1 && !valid1) break;
        #pragma unroll
        for (int ct = 0; ct < 4; ++ct) {
            #pragma unroll
            for (int r = 0; r < 4; ++r) {
                int row = n0 + mt * 16 + quad * 4 + r;
                h_out[(size_t)row * HD + w * 64 + ct * 16 + l15] = f2bf(acc[mt][ct][r]);
            }
        }
        #pragma unroll
        for (int r = 0; r < 4; ++r) {
            float p = av[0] * acc[mt][0][r] + av[1] * acc[mt][1][r]
                    + av[2] * acc[mt][2][r] + av[3] * acc[mt][3][r];
            p += __shfl_xor(p, 1);
            p += __shfl_xor(p, 2);
            p += __shfl_xor(p, 4);
            p += __shfl_xor(p, 8);
            if (l15 == 0) {
                int row = n0 + mt * 16 + quad * 4 + r;
                dot_out[(size_t)row * HH + w] = p;
            }
        }
    }
}

// ---------------------------------------------------------------------------
// K4: scatter each edge into its CSR slot; compute ex = exp(leaky(hl+hr+he))
// for all 4 heads here (edge-parallel) so agg's inner loop needs no hr
// gather / exp / leaky.  packed[pos] = tail index; exE[pos][h] = ex.
// ---------------------------------------------------------------------------
__global__ void scatter_kernel(const int* __restrict__ head, const int* __restrict__ tail,
                               const int* __restrict__ etype,
                               const float* __restrict__ hl, const float* __restrict__ hr,
                               const float* __restrict__ he,
                               int* __restrict__ cursor, int* __restrict__ packed,
                               float* __restrict__ exE) {
    int e = blockIdx.x * 256 + threadIdx.x;   // NE % 256 == 0
    int h0 = head[e];
    int tl = tail[e];
    int ty = etype[e];
    float4 L = *(const float4*)(hl + (size_t)h0 * HH);
    float4 R = *(const float4*)(hr + (size_t)tl * HH);
    float4 T = *(const float4*)(he + ty * HH);
    float s0 = L.x + R.x + T.x;
    float s1 = L.y + R.y + T.y;
    float s2 = L.z + R.z + T.z;
    float s3 = L.w + R.w + T.w;
    s0 = (s0 > 0.f) ? s0 : NEG_SLOPE * s0;
    s1 = (s1 > 0.f) ? s1 : NEG_SLOPE * s1;
    s2 = (s2 > 0.f) ? s2 : NEG_SLOPE * s2;
    s3 = (s3 > 0.f) ? s3 : NEG_SLOPE * s3;
    float w0 = __expf(s0), w1 = __expf(s1), w2 = __expf(s2), w3 = __expf(s3);
    int pos = atomicAdd(&cursor[h0], 1);
    packed[pos] = tl;
    *(float4*)(exE + (size_t)pos * HH) = make_float4(w0, w1, w2, w3);
}

// ---------------------------------------------------------------------------
// K5: aggregation. One wave per head node; 4 edges in flight per iteration:
// lane = (g,q), g=lane>>4 picks edge i+g, q=lane&15 owns cols 16q..16q+15
// (head h=q>>2). Weights come precomputed from exE (sequential CSR read).
// Cross-edge-stream combine via shfl_xor(16)/(32) at the end.
// ---------------------------------------------------------------------------
__global__ __launch_bounds__(256) void agg_kernel(const int* __restrict__ row_start,
                                                  const int* __restrict__ packed,
                                                  const float* __restrict__ exE,
                                                  const unsigned short* __restrict__ h_tail, // bf16
                                                  float* __restrict__ out) {
    const int wave = threadIdx.x >> 6;
    const int lane = threadIdx.x & 63;
    const int n = blockIdx.x * 4 + wave;      // N_HEADN % 4 == 0
    const int s = row_start[n];
    const int e = row_start[n + 1];
    const int g = lane >> 4;      // edge sub-stream 0..3
    const int q = lane & 15;      // column group: cols 16q..16q+15
    const int h = q >> 2;         // attention head for these cols

    float acc[16];
    #pragma unroll
    for (int c = 0; c < 16; ++c) acc[c] = 0.f;
    float z = 0.f;

    for (int i = s; i < e; i += 4) {
        const int ei = i + g;
        if (ei < e) {
            const int tl = packed[ei];
            const float w = exE[(size_t)ei * HH + h];
            const uint4* p = (const uint4*)(h_tail + (size_t)tl * HD + q * 16);
            uint4 u0 = p[0];
            uint4 u1 = p[1];
            #pragma unroll
            for (int j = 0; j < 4; ++j) {
                unsigned u = ((const unsigned*)&u0)[j];
                acc[2 * j]     += w * __uint_as_float(u << 16);
                acc[2 * j + 1] += w * __uint_as_float(u & 0xFFFF0000u);
            }
            #pragma unroll
            for (int j = 0; j < 4; ++j) {
                unsigned u = ((const unsigned*)&u1)[j];
                acc[8 + 2 * j]     += w * __uint_as_float(u << 16);
                acc[8 + 2 * j + 1] += w * __uint_as_float(u & 0xFFFF0000u);
            }
            z += w;
        }
    }

    // combine the 4 edge sub-streams (lane ^ 16, lane ^ 32)
    #pragma unroll
    for (int c = 0; c < 16; ++c) {
        acc[c] += __shfl_xor(acc[c], 16);
        acc[c] += __shfl_xor(acc[c], 32);
    }
    z += __shfl_xor(z, 16);
    z += __shfl_xor(z, 32);

    // lane writes cols q*16 + g*4 .. +3 from acc[g*4 .. g*4+3]
    float4 o;
    if (z > 0.f) {
        o.x = acc[g * 4 + 0] / z;
        o.y = acc[g * 4 + 1] / z;
        o.z = acc[g * 4 + 2] / z;
        o.w = acc[g * 4 + 3] / z;
        o.x = (o.x > 0.f) ? o.x : expm1f(o.x);
        o.y = (o.y > 0.f) ? o.y : expm1f(o.y);
        o.z = (o.z > 0.f) ? o.z : expm1f(o.z);
        o.w = (o.w > 0.f) ? o.w : expm1f(o.w);
    } else {
        o = make_float4(0.f, 0.f, 0.f, 0.f);
    }
    ((float4*)(out + (size_t)n * HD))[q * 4 + g] = o;
}

// ---------------------------------------------------------------------------
extern "C" void kernel_launch(void* const* d_in, const int* in_sizes, int n_in,
                              void* d_out, int out_size, void* d_ws, size_t ws_size,
                              hipStream_t stream) {
    const float* head_feature = (const float*)d_in[0];
    const float* tail_feature = (const float*)d_in[1];
    const int*   edge_list    = (const int*)d_in[2];   // [2, E]
    const int*   tmp_edge     = (const int*)d_in[3];   // [E]
    const float* W            = (const float*)d_in[4];
    const float* W_e          = (const float*)d_in[5];
    const float* edge_emb     = (const float*)d_in[6];
    const float* a_l          = (const float*)d_in[7];
    const float* a_r          = (const float*)d_in[8];
    const float* a_e          = (const float*)d_in[9];
    const int* head_ind = edge_list;
    const int* tail_ind = edge_list + NE;

    // Workspace carve-up (~44 MB), 16B-aligned chunks first
    char* ws = (char*)d_ws;
    unsigned short* h_tail = (unsigned short*)ws; ws += sizeof(unsigned short) * (size_t)N_TAILN * HD; // 25.6 MB
    float* exE       = (float*)ws; ws += sizeof(float) * (size_t)NE * HH;        // 12.8 MB
    short* Wt        = (short*)ws; ws += sizeof(short) * 256 * 256;              // 128 KB
    float* hl        = (float*)ws; ws += sizeof(float) * (size_t)N_HEADN * HH;   // 0.8 MB
    float* hr        = (float*)ws; ws += sizeof(float) * (size_t)N_TAILN * HH;   // 0.8 MB
    float* waT       = (float*)ws; ws += sizeof(float) * HH * 256;               // 4 KB
    float* he        = (float*)ws; ws += sizeof(float) * 32;                     // padded
    int*   packed    = (int*)ws;   ws += sizeof(int) * (size_t)NE;               // 3.2 MB
    int*   counts    = (int*)ws;   ws += sizeof(int) * (size_t)N_HEADN;          // 0.2 MB
    int*   row_start = (int*)ws;   ws += sizeof(int) * (size_t)(N_HEADN + 4);    // 0.2 MB
    int*   cursor    = (int*)ws;   ws += sizeof(int) * (size_t)N_HEADN;          // 0.2 MB
    int*   blockSums = (int*)ws;   ws += sizeof(int) * 256;
    int*   blockOff  = (int*)ws;   ws += sizeof(int) * 256;

    hipMemsetAsync(counts, 0, sizeof(int) * (size_t)N_HEADN, stream);

    // fused small prep (waT | he | Wt) — one dispatch, blocks run concurrently
    hipLaunchKernelGGL(prep_kernel, dim3(258), dim3(256), 0, stream,
                       W, a_l, W_e, a_e, edge_emb, waT, he, Wt);

    hipLaunchKernelGGL(hist_kernel, dim3(NE / 256), dim3(256), 0, stream,
                       head_ind, counts);
    hipLaunchKernelGGL(blocksum_kernel, dim3(NB_SCAN), dim3(256), 0, stream,
                       counts, blockSums);
    hipLaunchKernelGGL(blockscan_kernel, dim3(1), dim3(256), 0, stream,
                       blockSums, blockOff);
    hipLaunchKernelGGL(rowstart_kernel, dim3(NB_SCAN), dim3(256), 0, stream,
                       counts, blockOff, row_start, cursor);

    hipLaunchKernelGGL(head_dot_kernel, dim3(N_HEADN / 4), dim3(256), 0, stream,
                       head_feature, waT, hl);
    hipLaunchKernelGGL(proj_mfma_kernel, dim3((N_TAILN + 31) / 32), dim3(256), 0, stream,
                       tail_feature, Wt, a_r, h_tail, hr, N_TAILN);

    hipLaunchKernelGGL(scatter_kernel, dim3(NE / 256), dim3(256), 0, stream,
                       head_ind, tail_ind, tmp_edge, hl, hr, he, cursor, packed, exE);

    hipLaunchKernelGGL(agg_kernel, dim3(N_HEADN / 4), dim3(256), 0, stream,
                       row_start, packed, exE, h_tail, (float*)d_out);
}

// Round 2
// 370.829 us; speedup vs baseline: 1.1487x; 1.0017x over previous
//
#include <hip/hip_runtime.h>
#include <hip/hip_bf16.h>
#include <math.h>

// Problem constants (from reference)
#define N_HEADN 50000
#define N_TAILN 50000
#define NE      800000
#define F_IN    256
#define HH      4
#define HD      256   // H*D
#define FE      64
#define N_ETYPES 5
#define NEG_SLOPE 0.2f
#define NB_SCAN ((N_HEADN + 255) / 256)   // 196
#define NB_CVT  ((N_TAILN * F_IN) / (256 * 16))   // 3125 blocks, 16 elems/thread

typedef __attribute__((ext_vector_type(8))) short bf16x8;
typedef __attribute__((ext_vector_type(4))) float f32x4;

// bf16 <-> fp32 (RNE), bit-level
static __device__ __forceinline__ unsigned short f2bf(float f) {
    unsigned u = __float_as_uint(f);
    return (unsigned short)((u + 0x7FFF + ((u >> 16) & 1)) >> 16);
}
static __device__ __forceinline__ float bf2f(unsigned short u) {
    return __uint_as_float((unsigned)u << 16);
}

// ---------------------------------------------------------------------------
// K_prep (fused):
//   blocks 0..NB_CVT-1      : Xb = bf16(X_tail)   (streaming cvt, 16 el/thread)
//   block  NB_CVT           : waT[h][k] = sum_d a_l[h][d] * W[k][h*64+d]
//   block  NB_CVT+1         : he[ty][h]
//   blocks NB_CVT+2 ..+257  : Wt[n][k] = bf16(W[k][n])
// ---------------------------------------------------------------------------
__global__ __launch_bounds__(256) void prep_kernel(const float* __restrict__ X,
                                                   unsigned short* __restrict__ Xb,
                                                   const float* __restrict__ W,
                                                   const float* __restrict__ a_l,
                                                   const float* __restrict__ W_e,
                                                   const float* __restrict__ a_e,
                                                   const float* __restrict__ edge_emb,
                                                   float* __restrict__ waT,
                                                   float* __restrict__ heo,
                                                   short* __restrict__ Wt) {
    const int b = blockIdx.x;
    if (b < NB_CVT) {
        size_t t = (size_t)b * 256 + threadIdx.x;   // element-group index
        const float4* xp = (const float4*)X + t * 4;
        float4 v0 = xp[0], v1 = xp[1], v2 = xp[2], v3 = xp[3];
        bf16x8 o0, o1;
        o0[0] = (short)f2bf(v0.x); o0[1] = (short)f2bf(v0.y);
        o0[2] = (short)f2bf(v0.z); o0[3] = (short)f2bf(v0.w);
        o0[4] = (short)f2bf(v1.x); o0[5] = (short)f2bf(v1.y);
        o0[6] = (short)f2bf(v1.z); o0[7] = (short)f2bf(v1.w);
        o1[0] = (short)f2bf(v2.x); o1[1] = (short)f2bf(v2.y);
        o1[2] = (short)f2bf(v2.z); o1[3] = (short)f2bf(v2.w);
        o1[4] = (short)f2bf(v3.x); o1[5] = (short)f2bf(v3.y);
        o1[6] = (short)f2bf(v3.z); o1[7] = (short)f2bf(v3.w);
        bf16x8* op = (bf16x8*)(Xb + t * 16);
        op[0] = o0;
        op[1] = o1;
    } else if (b == NB_CVT) {
        int k = threadIdx.x;   // 0..255
        #pragma unroll
        for (int h = 0; h < HH; ++h) {
            float s = 0.f;
            for (int d = 0; d < 64; ++d) s += a_l[h * 64 + d] * W[(size_t)k * HD + h * 64 + d];
            waT[h * 256 + k] = s;
        }
    } else if (b == NB_CVT + 1) {
        __shared__ float wae[FE][HH];
        int t = threadIdx.x;          // 256 threads = 64 k x 4 h
        int k = t >> 2, h = t & 3;
        float s = 0.f;
        for (int f = 0; f < 64; ++f) s += a_e[h * 64 + f] * W_e[(size_t)k * (FE * HH) + h * 64 + f];
        wae[k][h] = s;
        __syncthreads();
        if (t < N_ETYPES * HH) {
            int ty = t >> 2, hh = t & 3;
            float acc = 0.f;
            for (int kk = 0; kk < FE; ++kk) acc += edge_emb[ty * FE + kk] * wae[kk][hh];
            heo[ty * HH + hh] = acc;
        }
    } else {
        int n = b - (NB_CVT + 2), k = threadIdx.x;
        Wt[(size_t)n * 256 + k] = (short)f2bf(W[(size_t)k * 256 + n]);
    }
}

// ---------------------------------------------------------------------------
// K1: histogram of head indices
// ---------------------------------------------------------------------------
__global__ void hist_kernel(const int* __restrict__ head, int* __restrict__ counts) {
    int e = blockIdx.x * 256 + threadIdx.x;   // NE % 256 == 0
    atomicAdd(&counts[head[e]], 1);
}

// ---------------------------------------------------------------------------
// K2a/b/c: parallel 3-phase exclusive scan of counts -> row_start, cursor
// ---------------------------------------------------------------------------
__global__ void blocksum_kernel(const int* __restrict__ counts, int* __restrict__ blockSums) {
    __shared__ int s[256];
    int t = threadIdx.x, j = blockIdx.x * 256 + t;
    s[t] = (j < N_HEADN) ? counts[j] : 0;
    __syncthreads();
    for (int off = 128; off > 0; off >>= 1) {
        if (t < off) s[t] += s[t + off];
        __syncthreads();
    }
    if (t == 0) blockSums[blockIdx.x] = s[0];
}

__global__ void blockscan_kernel(const int* __restrict__ blockSums, int* __restrict__ blockOff) {
    __shared__ int s[256];
    int t = threadIdx.x;
    int v = (t < NB_SCAN) ? blockSums[t] : 0;
    s[t] = v;
    __syncthreads();
    for (int off = 1; off < 256; off <<= 1) {
        int u = (t >= off) ? s[t - off] : 0;
        __syncthreads();
        s[t] += u;
        __syncthreads();
    }
    if (t < NB_SCAN) blockOff[t] = s[t] - v;
}

__global__ void rowstart_kernel(const int* __restrict__ counts, const int* __restrict__ blockOff,
                                int* __restrict__ row_start, int* __restrict__ cursor) {
    __shared__ int s[256];
    int t = threadIdx.x, j = blockIdx.x * 256 + t;
    int c = (j < N_HEADN) ? counts[j] : 0;
    s[t] = c;
    __syncthreads();
    for (int off = 1; off < 256; off <<= 1) {
        int u = (t >= off) ? s[t - off] : 0;
        __syncthreads();
        s[t] += u;
        __syncthreads();
    }
    int excl = blockOff[blockIdx.x] + s[t] - c;
    if (j < N_HEADN) {
        row_start[j] = excl;
        cursor[j]    = excl;
        if (j == N_HEADN - 1) row_start[N_HEADN] = excl + c;
    }
}

// ---------------------------------------------------------------------------
// K3a: hl = X_head @ waT^T  (thin GEMM, memory-bound). One wave per row.
// ---------------------------------------------------------------------------
__global__ __launch_bounds__(256) void head_dot_kernel(const float* __restrict__ X,
                                                       const float* __restrict__ waT,
                                                       float* __restrict__ hl) {
    const int wave = threadIdx.x >> 6;
    const int lane = threadIdx.x & 63;
    const int n = blockIdx.x * 4 + wave;   // N_HEADN % 4 == 0
    float4 x = ((const float4*)(X + (size_t)n * F_IN))[lane];
    float p[HH];
    #pragma unroll
    for (int h = 0; h < HH; ++h) {
        float4 w = ((const float4*)(waT + h * 256))[lane];
        p[h] = x.x * w.x + x.y * w.y + x.z * w.z + x.w * w.w;
    }
    #pragma unroll
    for (int off = 1; off < 64; off <<= 1) {
        #pragma unroll
        for (int h = 0; h < HH; ++h) p[h] += __shfl_xor(p[h], off);
    }
    if (lane < HH) hl[(size_t)n * HH + lane] = p[lane];
}

// ---------------------------------------------------------------------------
// K3b: h_tail = Xb(bf16) @ W via bf16 MFMA (16x16x32), fp32 accum.
// A-frag is now a single 16B load (Xb pre-converted in prep); K-loop fully
// unrolled so all loads can be hoisted into flight (latency -> ILP).
// A-frag: A[m=lane&15][k=quad*8+j]  B-frag: B[k=quad*8+j][n=lane&15]
// C/D:    col=lane&15, row=quad*4+reg  [m89-verified]
// ---------------------------------------------------------------------------
__global__ __launch_bounds__(256) void proj_mfma_kernel(const unsigned short* __restrict__ Xb,
                                                        const short* __restrict__ Wt,
                                                        const float* __restrict__ a,
                                                        unsigned short* __restrict__ h_out,
                                                        float* __restrict__ dot_out,
                                                        int N) {
    const int tid  = threadIdx.x;
    const int w    = tid >> 6;          // wave = head index
    const int lane = tid & 63;
    const int quad = lane >> 4;
    const int l15  = lane & 15;
    const int n0   = blockIdx.x * 32;

    const bool valid1 = (n0 + 16) < N;  // tile 1 present (N % 16 == 0)

    f32x4 acc[2][4];
    #pragma unroll
    for (int mt = 0; mt < 2; ++mt)
        #pragma unroll
        for (int ct = 0; ct < 4; ++ct)
            acc[mt][ct] = (f32x4){0.f, 0.f, 0.f, 0.f};

    const unsigned short* xbase0 = Xb + (size_t)(n0 + l15) * F_IN + quad * 8;
    const unsigned short* xbase1 = Xb + (size_t)(n0 + 16 + l15) * F_IN + quad * 8;
    const short* wbase  = Wt + (size_t)(w * 64 + l15) * 256 + quad * 8;

    #pragma unroll
    for (int k0 = 0; k0 < 256; k0 += 32) {
        bf16x8 a0 = *(const bf16x8*)(xbase0 + k0);
        bf16x8 a1;
        if (valid1) a1 = *(const bf16x8*)(xbase1 + k0);
        #pragma unroll
        for (int ct = 0; ct < 4; ++ct) {
            bf16x8 bfrag = *(const bf16x8*)(wbase + (size_t)ct * 16 * 256 + k0);
            acc[0][ct] = __builtin_amdgcn_mfma_f32_16x16x32_bf16(a0, bfrag, acc[0][ct], 0, 0, 0);
            if (valid1)
                acc[1][ct] = __builtin_amdgcn_mfma_f32_16x16x32_bf16(a1, bfrag, acc[1][ct], 0, 0, 0);
        }
    }

    float av[4];
    #pragma unroll
    for (int ct = 0; ct < 4; ++ct) av[ct] = a[w * 64 + ct * 16 + l15];

    #pragma unroll
    for (int mt = 0; mt < 2; ++mt) {
        if (mt == 1 && !valid1) break;
        #pragma unroll
        for (int ct = 0; ct < 4; ++ct) {
            #pragma unroll
            for (int r = 0; r < 4; ++r) {
                int row = n0 + mt * 16 + quad * 4 + r;
                h_out[(size_t)row * HD + w * 64 + ct * 16 + l15] = f2bf(acc[mt][ct][r]);
            }
        }
        #pragma unroll
        for (int r = 0; r < 4; ++r) {
            float p = av[0] * acc[mt][0][r] + av[1] * acc[mt][1][r]
                    + av[2] * acc[mt][2][r] + av[3] * acc[mt][3][r];
            p += __shfl_xor(p, 1);
            p += __shfl_xor(p, 2);
            p += __shfl_xor(p, 4);
            p += __shfl_xor(p, 8);
            if (l15 == 0) {
                int row = n0 + mt * 16 + quad * 4 + r;
                dot_out[(size_t)row * HH + w] = p;
            }
        }
    }
}

// ---------------------------------------------------------------------------
// K4: scatter each edge into its CSR slot; compute ex = exp(leaky(hl+hr+he))
// for all 4 heads here (edge-parallel). packed[pos] = tail; exE[pos][h] = ex.
// ---------------------------------------------------------------------------
__global__ void scatter_kernel(const int* __restrict__ head, const int* __restrict__ tail,
                               const int* __restrict__ etype,
                               const float* __restrict__ hl, const float* __restrict__ hr,
                               const float* __restrict__ he,
                               int* __restrict__ cursor, int* __restrict__ packed,
                               float* __restrict__ exE) {
    int e = blockIdx.x * 256 + threadIdx.x;   // NE % 256 == 0
    int h0 = head[e];
    int tl = tail[e];
    int ty = etype[e];
    float4 L = *(const float4*)(hl + (size_t)h0 * HH);
    float4 R = *(const float4*)(hr + (size_t)tl * HH);
    float4 T = *(const float4*)(he + ty * HH);
    float s0 = L.x + R.x + T.x;
    float s1 = L.y + R.y + T.y;
    float s2 = L.z + R.z + T.z;
    float s3 = L.w + R.w + T.w;
    s0 = (s0 > 0.f) ? s0 : NEG_SLOPE * s0;
    s1 = (s1 > 0.f) ? s1 : NEG_SLOPE * s1;
    s2 = (s2 > 0.f) ? s2 : NEG_SLOPE * s2;
    s3 = (s3 > 0.f) ? s3 : NEG_SLOPE * s3;
    float w0 = __expf(s0), w1 = __expf(s1), w2 = __expf(s2), w3 = __expf(s3);
    int pos = atomicAdd(&cursor[h0], 1);
    packed[pos] = tl;
    *(float4*)(exE + (size_t)pos * HH) = make_float4(w0, w1, w2, w3);
}

// ---------------------------------------------------------------------------
// K5: aggregation. One wave per head node; 4 edges in flight per iteration:
// lane = (g,q), g=lane>>4 picks edge i+g, q=lane&15 owns cols 16q..16q+15
// (head h=q>>2). Weights precomputed in exE (sequential CSR read).
// ---------------------------------------------------------------------------
__global__ __launch_bounds__(256) void agg_kernel(const int* __restrict__ row_start,
                                                  const int* __restrict__ packed,
                                                  const float* __restrict__ exE,
                                                  const unsigned short* __restrict__ h_tail, // bf16
                                                  float* __restrict__ out) {
    const int wave = threadIdx.x >> 6;
    const int lane = threadIdx.x & 63;
    const int n = blockIdx.x * 4 + wave;      // N_HEADN % 4 == 0
    const int s = row_start[n];
    const int e = row_start[n + 1];
    const int g = lane >> 4;      // edge sub-stream 0..3
    const int q = lane & 15;      // column group: cols 16q..16q+15
    const int h = q >> 2;         // attention head for these cols

    float acc[16];
    #pragma unroll
    for (int c = 0; c < 16; ++c) acc[c] = 0.f;
    float z = 0.f;

    for (int i = s; i < e; i += 4) {
        const int ei = i + g;
        if (ei < e) {
            const int tl = packed[ei];
            const float w = exE[(size_t)ei * HH + h];
            const uint4* p = (const uint4*)(h_tail + (size_t)tl * HD + q * 16);
            uint4 u0 = p[0];
            uint4 u1 = p[1];
            #pragma unroll
            for (int j = 0; j < 4; ++j) {
                unsigned u = ((const unsigned*)&u0)[j];
                acc[2 * j]     += w * __uint_as_float(u << 16);
                acc[2 * j + 1] += w * __uint_as_float(u & 0xFFFF0000u);
            }
            #pragma unroll
            for (int j = 0; j < 4; ++j) {
                unsigned u = ((const unsigned*)&u1)[j];
                acc[8 + 2 * j]     += w * __uint_as_float(u << 16);
                acc[8 + 2 * j + 1] += w * __uint_as_float(u & 0xFFFF0000u);
            }
            z += w;
        }
    }

    // combine the 4 edge sub-streams (lane ^ 16, lane ^ 32)
    #pragma unroll
    for (int c = 0; c < 16; ++c) {
        acc[c] += __shfl_xor(acc[c], 16);
        acc[c] += __shfl_xor(acc[c], 32);
    }
    z += __shfl_xor(z, 16);
    z += __shfl_xor(z, 32);

    // lane writes cols q*16 + g*4 .. +3 from acc[g*4 .. g*4+3]
    float4 o;
    if (z > 0.f) {
        o.x = acc[g * 4 + 0] / z;
        o.y = acc[g * 4 + 1] / z;
        o.z = acc[g * 4 + 2] / z;
        o.w = acc[g * 4 + 3] / z;
        o.x = (o.x > 0.f) ? o.x : expm1f(o.x);
        o.y = (o.y > 0.f) ? o.y : expm1f(o.y);
        o.z = (o.z > 0.f) ? o.z : expm1f(o.z);
        o.w = (o.w > 0.f) ? o.w : expm1f(o.w);
    } else {
        o = make_float4(0.f, 0.f, 0.f, 0.f);
    }
    ((float4*)(out + (size_t)n * HD))[q * 4 + g] = o;
}

// ---------------------------------------------------------------------------
extern "C" void kernel_launch(void* const* d_in, const int* in_sizes, int n_in,
                              void* d_out, int out_size, void* d_ws, size_t ws_size,
                              hipStream_t stream) {
    const float* head_feature = (const float*)d_in[0];
    const float* tail_feature = (const float*)d_in[1];
    const int*   edge_list    = (const int*)d_in[2];   // [2, E]
    const int*   tmp_edge     = (const int*)d_in[3];   // [E]
    const float* W            = (const float*)d_in[4];
    const float* W_e          = (const float*)d_in[5];
    const float* edge_emb     = (const float*)d_in[6];
    const float* a_l          = (const float*)d_in[7];
    const float* a_r          = (const float*)d_in[8];
    const float* a_e          = (const float*)d_in[9];
    const int* head_ind = edge_list;
    const int* tail_ind = edge_list + NE;

    // Workspace carve-up (~54 MB), 16B-aligned chunks first.
    // Xb (bf16 tail features, dead after proj) ALIASES exE+packed (born in
    // scatter) — region R sized max(25.6, 16) MB.
    char* ws = (char*)d_ws;
    unsigned short* h_tail = (unsigned short*)ws; ws += sizeof(unsigned short) * (size_t)N_TAILN * HD; // 25.6 MB
    unsigned short* Xb = (unsigned short*)ws;      // 25.6 MB region R
    float* exE    = (float*)(void*)Xb;                                          // alias: 12.8 MB
    int*   packed = (int*)(void*)((char*)(void*)Xb + sizeof(float) * (size_t)NE * HH); // alias: 3.2 MB
    ws += sizeof(unsigned short) * (size_t)N_TAILN * HD;
    short* Wt        = (short*)ws; ws += sizeof(short) * 256 * 256;              // 128 KB
    float* hl        = (float*)ws; ws += sizeof(float) * (size_t)N_HEADN * HH;   // 0.8 MB
    float* hr        = (float*)ws; ws += sizeof(float) * (size_t)N_TAILN * HH;   // 0.8 MB
    float* waT       = (float*)ws; ws += sizeof(float) * HH * 256;               // 4 KB
    float* he        = (float*)ws; ws += sizeof(float) * 32;                     // padded
    int*   counts    = (int*)ws;   ws += sizeof(int) * (size_t)N_HEADN;          // 0.2 MB
    int*   row_start = (int*)ws;   ws += sizeof(int) * (size_t)(N_HEADN + 4);    // 0.2 MB
    int*   cursor    = (int*)ws;   ws += sizeof(int) * (size_t)N_HEADN;          // 0.2 MB
    int*   blockSums = (int*)ws;   ws += sizeof(int) * 256;
    int*   blockOff  = (int*)ws;   ws += sizeof(int) * 256;

    hipMemsetAsync(counts, 0, sizeof(int) * (size_t)N_HEADN, stream);

    // fused prep: Xb cvt | waT | he | Wt — one dispatch
    hipLaunchKernelGGL(prep_kernel, dim3(NB_CVT + 258), dim3(256), 0, stream,
                       tail_feature, Xb, W, a_l, W_e, a_e, edge_emb, waT, he, Wt);

    hipLaunchKernelGGL(hist_kernel, dim3(NE / 256), dim3(256), 0, stream,
                       head_ind, counts);
    hipLaunchKernelGGL(blocksum_kernel, dim3(NB_SCAN), dim3(256), 0, stream,
                       counts, blockSums);
    hipLaunchKernelGGL(blockscan_kernel, dim3(1), dim3(256), 0, stream,
                       blockSums, blockOff);
    hipLaunchKernelGGL(rowstart_kernel, dim3(NB_SCAN), dim3(256), 0, stream,
                       counts, blockOff, row_start, cursor);

    hipLaunchKernelGGL(head_dot_kernel, dim3(N_HEADN / 4), dim3(256), 0, stream,
                       head_feature, waT, hl);
    hipLaunchKernelGGL(proj_mfma_kernel, dim3((N_TAILN + 31) / 32), dim3(256), 0, stream,
                       Xb, Wt, a_r, h_tail, hr, N_TAILN);

    hipLaunchKernelGGL(scatter_kernel, dim3(NE / 256), dim3(256), 0, stream,
                       head_ind, tail_ind, tmp_edge, hl, hr, he, cursor, packed, exE);

    hipLaunchKernelGGL(agg_kernel, dim3(N_HEADN / 4), dim3(256), 0, stream,
                       row_start, packed, exE, h_tail, (float*)d_out);
}

// Round 3
// 360.217 us; speedup vs baseline: 1.1825x; 1.0295x over previous
//
#include <hip/hip_runtime.h>
#include <hip/hip_bf16.h>
#include <math.h>

// Problem constants (from reference)
#define N_HEADN 50000
#define N_TAILN 50000
#define NE      800000
#define F_IN    256
#define HH      4
#define HD      256   // H*D
#define FE      64
#define N_ETYPES 5
#define NEG_SLOPE 0.2f
#define NB_SCAN ((N_HEADN + 255) / 256)   // 196
#define NB_CVT  ((N_TAILN * F_IN) / (256 * 16))   // 3125 blocks, 16 elems/thread

typedef __attribute__((ext_vector_type(8))) short bf16x8;
typedef __attribute__((ext_vector_type(4))) float f32x4;

// bf16 <-> fp32 (RNE), bit-level
static __device__ __forceinline__ unsigned short f2bf(float f) {
    unsigned u = __float_as_uint(f);
    return (unsigned short)((u + 0x7FFF + ((u >> 16) & 1)) >> 16);
}
static __device__ __forceinline__ float bf2f(unsigned short u) {
    return __uint_as_float((unsigned)u << 16);
}

// ---------------------------------------------------------------------------
// K_prep (fused):
//   blocks 0..NB_CVT-1        : Xb = bf16(X_tail)  (streaming cvt, 16 el/thr)
//   block  NB_CVT             : waT[h][k] = sum_d a_l[h][d] * W[k][h*64+d]
//   block  NB_CVT+1           : he[ty][h]
//   blocks NB_CVT+2 ..+257    : Wt[n][k] = bf16(W[k][n])
//   blocks NB_CVT+258 ..+453  : counts[] = 0   (replaces hipMemsetAsync)
// ---------------------------------------------------------------------------
__global__ __launch_bounds__(256) void prep_kernel(const float* __restrict__ X,
                                                   unsigned short* __restrict__ Xb,
                                                   const float* __restrict__ W,
                                                   const float* __restrict__ a_l,
                                                   const float* __restrict__ W_e,
                                                   const float* __restrict__ a_e,
                                                   const float* __restrict__ edge_emb,
                                                   float* __restrict__ waT,
                                                   float* __restrict__ heo,
                                                   short* __restrict__ Wt,
                                                   int* __restrict__ counts) {
    const int b = blockIdx.x;
    if (b < NB_CVT) {
        size_t t = (size_t)b * 256 + threadIdx.x;   // element-group index
        const float4* xp = (const float4*)X + t * 4;
        float4 v0 = xp[0], v1 = xp[1], v2 = xp[2], v3 = xp[3];
        bf16x8 o0, o1;
        o0[0] = (short)f2bf(v0.x); o0[1] = (short)f2bf(v0.y);
        o0[2] = (short)f2bf(v0.z); o0[3] = (short)f2bf(v0.w);
        o0[4] = (short)f2bf(v1.x); o0[5] = (short)f2bf(v1.y);
        o0[6] = (short)f2bf(v1.z); o0[7] = (short)f2bf(v1.w);
        o1[0] = (short)f2bf(v2.x); o1[1] = (short)f2bf(v2.y);
        o1[2] = (short)f2bf(v2.z); o1[3] = (short)f2bf(v2.w);
        o1[4] = (short)f2bf(v3.x); o1[5] = (short)f2bf(v3.y);
        o1[6] = (short)f2bf(v3.z); o1[7] = (short)f2bf(v3.w);
        bf16x8* op = (bf16x8*)(Xb + t * 16);
        op[0] = o0;
        op[1] = o1;
    } else if (b == NB_CVT) {
        int k = threadIdx.x;   // 0..255
        #pragma unroll
        for (int h = 0; h < HH; ++h) {
            float s = 0.f;
            for (int d = 0; d < 64; ++d) s += a_l[h * 64 + d] * W[(size_t)k * HD + h * 64 + d];
            waT[h * 256 + k] = s;
        }
    } else if (b == NB_CVT + 1) {
        __shared__ float wae[FE][HH];
        int t = threadIdx.x;          // 256 threads = 64 k x 4 h
        int k = t >> 2, h = t & 3;
        float s = 0.f;
        for (int f = 0; f < 64; ++f) s += a_e[h * 64 + f] * W_e[(size_t)k * (FE * HH) + h * 64 + f];
        wae[k][h] = s;
        __syncthreads();
        if (t < N_ETYPES * HH) {
            int ty = t >> 2, hh = t & 3;
            float acc = 0.f;
            for (int kk = 0; kk < FE; ++kk) acc += edge_emb[ty * FE + kk] * wae[kk][hh];
            heo[ty * HH + hh] = acc;
        }
    } else if (b < NB_CVT + 2 + 256) {
        int n = b - (NB_CVT + 2), k = threadIdx.x;
        Wt[(size_t)n * 256 + k] = (short)f2bf(W[(size_t)k * 256 + n]);
    } else {
        int j = (b - (NB_CVT + 258)) * 256 + threadIdx.x;
        if (j < N_HEADN) counts[j] = 0;
    }
}

// ---------------------------------------------------------------------------
// K1: histogram of head indices
// ---------------------------------------------------------------------------
__global__ void hist_kernel(const int* __restrict__ head, int* __restrict__ counts) {
    int e = blockIdx.x * 256 + threadIdx.x;   // NE % 256 == 0
    atomicAdd(&counts[head[e]], 1);
}

// ---------------------------------------------------------------------------
// K2a/b/c: parallel 3-phase exclusive scan of counts -> row_start, cursor
// ---------------------------------------------------------------------------
__global__ void blocksum_kernel(const int* __restrict__ counts, int* __restrict__ blockSums) {
    __shared__ int s[256];
    int t = threadIdx.x, j = blockIdx.x * 256 + t;
    s[t] = (j < N_HEADN) ? counts[j] : 0;
    __syncthreads();
    for (int off = 128; off > 0; off >>= 1) {
        if (t < off) s[t] += s[t + off];
        __syncthreads();
    }
    if (t == 0) blockSums[blockIdx.x] = s[0];
}

__global__ void blockscan_kernel(const int* __restrict__ blockSums, int* __restrict__ blockOff) {
    __shared__ int s[256];
    int t = threadIdx.x;
    int v = (t < NB_SCAN) ? blockSums[t] : 0;
    s[t] = v;
    __syncthreads();
    for (int off = 1; off < 256; off <<= 1) {
        int u = (t >= off) ? s[t - off] : 0;
        __syncthreads();
        s[t] += u;
        __syncthreads();
    }
    if (t < NB_SCAN) blockOff[t] = s[t] - v;
}

__global__ void rowstart_kernel(const int* __restrict__ counts, const int* __restrict__ blockOff,
                                int* __restrict__ row_start, int* __restrict__ cursor) {
    __shared__ int s[256];
    int t = threadIdx.x, j = blockIdx.x * 256 + t;
    int c = (j < N_HEADN) ? counts[j] : 0;
    s[t] = c;
    __syncthreads();
    for (int off = 1; off < 256; off <<= 1) {
        int u = (t >= off) ? s[t - off] : 0;
        __syncthreads();
        s[t] += u;
        __syncthreads();
    }
    int excl = blockOff[blockIdx.x] + s[t] - c;
    if (j < N_HEADN) {
        row_start[j] = excl;
        cursor[j]    = excl;
        if (j == N_HEADN - 1) row_start[N_HEADN] = excl + c;
    }
}

// ---------------------------------------------------------------------------
// K3a: hl = X_head @ waT^T  (thin GEMM, memory-bound). One wave per row.
// ---------------------------------------------------------------------------
__global__ __launch_bounds__(256) void head_dot_kernel(const float* __restrict__ X,
                                                       const float* __restrict__ waT,
                                                       float* __restrict__ hl) {
    const int wave = threadIdx.x >> 6;
    const int lane = threadIdx.x & 63;
    const int n = blockIdx.x * 4 + wave;   // N_HEADN % 4 == 0
    float4 x = ((const float4*)(X + (size_t)n * F_IN))[lane];
    float p[HH];
    #pragma unroll
    for (int h = 0; h < HH; ++h) {
        float4 w = ((const float4*)(waT + h * 256))[lane];
        p[h] = x.x * w.x + x.y * w.y + x.z * w.z + x.w * w.w;
    }
    #pragma unroll
    for (int off = 1; off < 64; off <<= 1) {
        #pragma unroll
        for (int h = 0; h < HH; ++h) p[h] += __shfl_xor(p[h], off);
    }
    if (lane < HH) hl[(size_t)n * HH + lane] = p[lane];
}

// ---------------------------------------------------------------------------
// K3b: h_tail = Xb(bf16) @ W via bf16 MFMA (16x16x32), fp32 accum.
// 4 M-tiles per wave (64 rows/block): each B-frag feeds 4 MFMAs instead of 2
// -> B-load instructions per output row cut 33%, Wt L2 traffic halved.
// Tail: clamp row-base to N-16 (duplicate stores of identical values, benign;
// requires N % 16 == 0, true for 50000).
// A-frag: A[m=lane&15][k=quad*8+j]  B-frag: B[k=quad*8+j][n=lane&15]
// C/D:    col=lane&15, row=quad*4+reg  [m89-verified]
// ---------------------------------------------------------------------------
__global__ __launch_bounds__(256) void proj_mfma_kernel(const unsigned short* __restrict__ Xb,
                                                        const short* __restrict__ Wt,
                                                        const float* __restrict__ a,
                                                        unsigned short* __restrict__ h_out,
                                                        float* __restrict__ dot_out,
                                                        int N) {
    const int tid  = threadIdx.x;
    const int w    = tid >> 6;          // wave = head index
    const int lane = tid & 63;
    const int quad = lane >> 4;
    const int l15  = lane & 15;
    const int n0   = blockIdx.x * 64;

    int rbase[4];
    #pragma unroll
    for (int mt = 0; mt < 4; ++mt) {
        int r = n0 + mt * 16;
        rbase[mt] = (r + 16 <= N) ? r : (N - 16);   // clamp tail tiles
    }

    f32x4 acc[4][4];
    #pragma unroll
    for (int mt = 0; mt < 4; ++mt)
        #pragma unroll
        for (int ct = 0; ct < 4; ++ct)
            acc[mt][ct] = (f32x4){0.f, 0.f, 0.f, 0.f};

    const short* wbase = Wt + (size_t)(w * 64 + l15) * 256 + quad * 8;
    const unsigned short* xb[4];
    #pragma unroll
    for (int mt = 0; mt < 4; ++mt)
        xb[mt] = Xb + (size_t)(rbase[mt] + l15) * F_IN + quad * 8;

    #pragma unroll 2
    for (int k0 = 0; k0 < 256; k0 += 32) {
        bf16x8 af[4];
        #pragma unroll
        for (int mt = 0; mt < 4; ++mt) af[mt] = *(const bf16x8*)(xb[mt] + k0);
        #pragma unroll
        for (int ct = 0; ct < 4; ++ct) {
            bf16x8 bfrag = *(const bf16x8*)(wbase + (size_t)ct * 16 * 256 + k0);
            #pragma unroll
            for (int mt = 0; mt < 4; ++mt)
                acc[mt][ct] = __builtin_amdgcn_mfma_f32_16x16x32_bf16(af[mt], bfrag, acc[mt][ct], 0, 0, 0);
        }
    }

    float av[4];
    #pragma unroll
    for (int ct = 0; ct < 4; ++ct) av[ct] = a[w * 64 + ct * 16 + l15];

    #pragma unroll
    for (int mt = 0; mt < 4; ++mt) {
        #pragma unroll
        for (int ct = 0; ct < 4; ++ct) {
            #pragma unroll
            for (int r = 0; r < 4; ++r) {
                int row = rbase[mt] + quad * 4 + r;
                h_out[(size_t)row * HD + w * 64 + ct * 16 + l15] = f2bf(acc[mt][ct][r]);
            }
        }
        #pragma unroll
        for (int r = 0; r < 4; ++r) {
            float p = av[0] * acc[mt][0][r] + av[1] * acc[mt][1][r]
                    + av[2] * acc[mt][2][r] + av[3] * acc[mt][3][r];
            p += __shfl_xor(p, 1);
            p += __shfl_xor(p, 2);
            p += __shfl_xor(p, 4);
            p += __shfl_xor(p, 8);
            if (l15 == 0) {
                int row = rbase[mt] + quad * 4 + r;
                dot_out[(size_t)row * HH + w] = p;
            }
        }
    }
}

// ---------------------------------------------------------------------------
// K4: scatter each edge into its CSR slot; compute ex = exp(leaky(hl+hr+he))
// for all 4 heads here (edge-parallel). packed[pos] = tail; exE[pos][h] = ex.
// ---------------------------------------------------------------------------
__global__ void scatter_kernel(const int* __restrict__ head, const int* __restrict__ tail,
                               const int* __restrict__ etype,
                               const float* __restrict__ hl, const float* __restrict__ hr,
                               const float* __restrict__ he,
                               int* __restrict__ cursor, int* __restrict__ packed,
                               float* __restrict__ exE) {
    int e = blockIdx.x * 256 + threadIdx.x;   // NE % 256 == 0
    int h0 = head[e];
    int tl = tail[e];
    int ty = etype[e];
    float4 L = *(const float4*)(hl + (size_t)h0 * HH);
    float4 R = *(const float4*)(hr + (size_t)tl * HH);
    float4 T = *(const float4*)(he + ty * HH);
    float s0 = L.x + R.x + T.x;
    float s1 = L.y + R.y + T.y;
    float s2 = L.z + R.z + T.z;
    float s3 = L.w + R.w + T.w;
    s0 = (s0 > 0.f) ? s0 : NEG_SLOPE * s0;
    s1 = (s1 > 0.f) ? s1 : NEG_SLOPE * s1;
    s2 = (s2 > 0.f) ? s2 : NEG_SLOPE * s2;
    s3 = (s3 > 0.f) ? s3 : NEG_SLOPE * s3;
    float w0 = __expf(s0), w1 = __expf(s1), w2 = __expf(s2), w3 = __expf(s3);
    int pos = atomicAdd(&cursor[h0], 1);
    packed[pos] = tl;
    *(float4*)(exE + (size_t)pos * HH) = make_float4(w0, w1, w2, w3);
}

// ---------------------------------------------------------------------------
// K5: aggregation. One wave per head node. Chunked index-preload: one
// coalesced load grabs up to 64 edge indices per wave; per-edge tail comes
// from __shfl (2-cyc) instead of a dependent 500-cyc load -> h_tail gathers
// are address-independent and pipeline freely. 4 edges/iter, 16 cols/lane.
// ---------------------------------------------------------------------------
__global__ __launch_bounds__(256) void agg_kernel(const int* __restrict__ row_start,
                                                  const int* __restrict__ packed,
                                                  const float* __restrict__ exE,
                                                  const unsigned short* __restrict__ h_tail, // bf16
                                                  float* __restrict__ out) {
    const int wave = threadIdx.x >> 6;
    const int lane = threadIdx.x & 63;
    const int n = blockIdx.x * 4 + wave;      // N_HEADN % 4 == 0
    const int s = row_start[n];
    const int e = row_start[n + 1];
    const int g = lane >> 4;      // edge sub-stream 0..3
    const int q = lane & 15;      // column group: cols 16q..16q+15
    const int h = q >> 2;         // attention head for these cols

    float acc[16];
    #pragma unroll
    for (int c = 0; c < 16; ++c) acc[c] = 0.f;
    float z = 0.f;

    for (int base = s; base < e; base += 64) {
        const int cnt = (e - base < 64) ? (e - base) : 64;
        int myidx = 0;
        if (base + lane < e) myidx = packed[base + lane];
        #pragma unroll 4
        for (int i = 0; i < cnt; i += 4) {
            const int j = i + g;
            const int tl = __shfl(myidx, j);
            if (j < cnt) {
                const float w = exE[(size_t)(base + j) * HH + h];
                const uint4* p = (const uint4*)(h_tail + (size_t)tl * HD + q * 16);
                uint4 u0 = p[0];
                uint4 u1 = p[1];
                #pragma unroll
                for (int jj = 0; jj < 4; ++jj) {
                    unsigned u = ((const unsigned*)&u0)[jj];
                    acc[2 * jj]     += w * __uint_as_float(u << 16);
                    acc[2 * jj + 1] += w * __uint_as_float(u & 0xFFFF0000u);
                }
                #pragma unroll
                for (int jj = 0; jj < 4; ++jj) {
                    unsigned u = ((const unsigned*)&u1)[jj];
                    acc[8 + 2 * jj]     += w * __uint_as_float(u << 16);
                    acc[8 + 2 * jj + 1] += w * __uint_as_float(u & 0xFFFF0000u);
                }
                z += w;
            }
        }
    }

    // combine the 4 edge sub-streams (lane ^ 16, lane ^ 32)
    #pragma unroll
    for (int c = 0; c < 16; ++c) {
        acc[c] += __shfl_xor(acc[c], 16);
        acc[c] += __shfl_xor(acc[c], 32);
    }
    z += __shfl_xor(z, 16);
    z += __shfl_xor(z, 32);

    // lane writes cols q*16 + g*4 .. +3 from acc[g*4 .. g*4+3]
    float4 o;
    if (z > 0.f) {
        o.x = acc[g * 4 + 0] / z;
        o.y = acc[g * 4 + 1] / z;
        o.z = acc[g * 4 + 2] / z;
        o.w = acc[g * 4 + 3] / z;
        o.x = (o.x > 0.f) ? o.x : expm1f(o.x);
        o.y = (o.y > 0.f) ? o.y : expm1f(o.y);
        o.z = (o.z > 0.f) ? o.z : expm1f(o.z);
        o.w = (o.w > 0.f) ? o.w : expm1f(o.w);
    } else {
        o = make_float4(0.f, 0.f, 0.f, 0.f);
    }
    ((float4*)(out + (size_t)n * HD))[q * 4 + g] = o;
}

// ---------------------------------------------------------------------------
extern "C" void kernel_launch(void* const* d_in, const int* in_sizes, int n_in,
                              void* d_out, int out_size, void* d_ws, size_t ws_size,
                              hipStream_t stream) {
    const float* head_feature = (const float*)d_in[0];
    const float* tail_feature = (const float*)d_in[1];
    const int*   edge_list    = (const int*)d_in[2];   // [2, E]
    const int*   tmp_edge     = (const int*)d_in[3];   // [E]
    const float* W            = (const float*)d_in[4];
    const float* W_e          = (const float*)d_in[5];
    const float* edge_emb     = (const float*)d_in[6];
    const float* a_l          = (const float*)d_in[7];
    const float* a_r          = (const float*)d_in[8];
    const float* a_e          = (const float*)d_in[9];
    const int* head_ind = edge_list;
    const int* tail_ind = edge_list + NE;

    // Workspace carve-up (~54 MB), 16B-aligned chunks first.
    // Xb (bf16 tail features, dead after proj) ALIASES exE+packed (born in
    // scatter) — region R sized max(25.6, 16) MB.
    char* ws = (char*)d_ws;
    unsigned short* h_tail = (unsigned short*)ws; ws += sizeof(unsigned short) * (size_t)N_TAILN * HD; // 25.6 MB
    unsigned short* Xb = (unsigned short*)ws;      // 25.6 MB region R
    float* exE    = (float*)(void*)Xb;                                          // alias: 12.8 MB
    int*   packed = (int*)(void*)((char*)(void*)Xb + sizeof(float) * (size_t)NE * HH); // alias: 3.2 MB
    ws += sizeof(unsigned short) * (size_t)N_TAILN * HD;
    short* Wt        = (short*)ws; ws += sizeof(short) * 256 * 256;              // 128 KB
    float* hl        = (float*)ws; ws += sizeof(float) * (size_t)N_HEADN * HH;   // 0.8 MB
    float* hr        = (float*)ws; ws += sizeof(float) * (size_t)N_TAILN * HH;   // 0.8 MB
    float* waT       = (float*)ws; ws += sizeof(float) * HH * 256;               // 4 KB
    float* he        = (float*)ws; ws += sizeof(float) * 32;                     // padded
    int*   counts    = (int*)ws;   ws += sizeof(int) * (size_t)N_HEADN;          // 0.2 MB
    int*   row_start = (int*)ws;   ws += sizeof(int) * (size_t)(N_HEADN + 4);    // 0.2 MB
    int*   cursor    = (int*)ws;   ws += sizeof(int) * (size_t)N_HEADN;          // 0.2 MB
    int*   blockSums = (int*)ws;   ws += sizeof(int) * 256;
    int*   blockOff  = (int*)ws;   ws += sizeof(int) * 256;

    // fused prep: Xb cvt | waT | he | Wt | counts=0 — one dispatch
    hipLaunchKernelGGL(prep_kernel, dim3(NB_CVT + 258 + NB_SCAN), dim3(256), 0, stream,
                       tail_feature, Xb, W, a_l, W_e, a_e, edge_emb, waT, he, Wt, counts);

    hipLaunchKernelGGL(hist_kernel, dim3(NE / 256), dim3(256), 0, stream,
                       head_ind, counts);
    hipLaunchKernelGGL(blocksum_kernel, dim3(NB_SCAN), dim3(256), 0, stream,
                       counts, blockSums);
    hipLaunchKernelGGL(blockscan_kernel, dim3(1), dim3(256), 0, stream,
                       blockSums, blockOff);
    hipLaunchKernelGGL(rowstart_kernel, dim3(NB_SCAN), dim3(256), 0, stream,
                       counts, blockOff, row_start, cursor);

    hipLaunchKernelGGL(head_dot_kernel, dim3(N_HEADN / 4), dim3(256), 0, stream,
                       head_feature, waT, hl);
    hipLaunchKernelGGL(proj_mfma_kernel, dim3((N_TAILN + 63) / 64), dim3(256), 0, stream,
                       Xb, Wt, a_r, h_tail, hr, N_TAILN);

    hipLaunchKernelGGL(scatter_kernel, dim3(NE / 256), dim3(256), 0, stream,
                       head_ind, tail_ind, tmp_edge, hl, hr, he, cursor, packed, exE);

    hipLaunchKernelGGL(agg_kernel, dim3(N_HEADN / 4), dim3(256), 0, stream,
                       row_start, packed, exE, h_tail, (float*)d_out);
}